// Round 14
// baseline (407.653 us; speedup 1.0000x reference)
//
#include <hip/hip_runtime.h>
#include <hip/hip_bf16.h>
#include <cstdint>

// B=2, C=256, H=W=256, P=4 -> h=w=64, L=4096, NH=8, D=32

typedef __attribute__((ext_vector_type(8))) short bf16x8;
typedef __attribute__((ext_vector_type(4))) float f32x4;
typedef __attribute__((ext_vector_type(4))) unsigned short u16x4;

#define SWZ(p, off) ((off) ^ (((p) & 7) << 4))

__device__ inline unsigned pk2bf(float a, float b) {
    unsigned ua = __builtin_bit_cast(unsigned, a);
    ua += 0x7fffu + ((ua >> 16) & 1u);
    unsigned ub = __builtin_bit_cast(unsigned, b);
    ub += 0x7fffu + ((ub >> 16) & 1u);
    return (ua >> 16) | (ub & 0xffff0000u);
}
__device__ inline unsigned short bf16of(float a) {
    unsigned ua = __builtin_bit_cast(unsigned, a);
    ua += 0x7fffu + ((ua >> 16) & 1u);
    return (unsigned short)(ua >> 16);
}
__device__ inline float bitf(unsigned u) { return __builtin_bit_cast(float, u); }
__device__ inline float bf2f(unsigned short u) { return bitf(((unsigned)u) << 16); }

// ---------------- W image packer: MFMA A-fragment order, bf16 ----------------
// W1 image: [16 rk][32 jt][64 lane] uint4 ; lane l = W1[j=jt*16+(l&15)][k=rk*32+8*(l>>4)..+7]
// W2 image: [16 rj][16 ct][64 lane] uint4 ; lane l = W2[c=ct*16+(l&15)][j=rj*32+8*(l>>4)..+7]
__global__ void build_wimg(const float* __restrict__ w1, const float* __restrict__ w2,
                           uint4* __restrict__ w1img, uint4* __restrict__ w2img) {
    int idx = blockIdx.x * 256 + threadIdx.x;
    if (idx < 32768) {
        int rk = idx >> 11, jt = (idx >> 6) & 31, l = idx & 63;
        int j = jt * 16 + (l & 15);
        int k0 = rk * 32 + 8 * (l >> 4);
        const float* s = w1 + j * 512 + k0;
        uint4 pk;
        pk.x = pk2bf(s[0], s[1]); pk.y = pk2bf(s[2], s[3]);
        pk.z = pk2bf(s[4], s[5]); pk.w = pk2bf(s[6], s[7]);
        w1img[idx] = pk;
    } else {
        int id2 = idx - 32768;  // < 16384
        int rj = id2 >> 10, ct = (id2 >> 6) & 15, l = id2 & 63;
        int c = ct * 16 + (l & 15);
        int j0 = rj * 32 + 8 * (l >> 4);
        const float* s = w2 + c * 512 + j0;
        uint4 pk;
        pk.x = pk2bf(s[0], s[1]); pk.y = pk2bf(s[2], s[3]);
        pk.z = pk2bf(s[4], s[5]); pk.w = pk2bf(s[6], s[7]);
        w2img[id2] = pk;
    }
}

// ---------------- fused maxpool 4x4 + LayerNorm -> NHWC bf16 [b][qy][qx][c] ----------------
__global__ __launch_bounds__(512) void poolln_k(
    const float* __restrict__ x, const float* __restrict__ src,
    const float* __restrict__ g, const float* __restrict__ bvec,
    unsigned short* __restrict__ q_sp, unsigned short* __restrict__ s_sp) {
    __shared__ __align__(16) float tile[16640];  // [256 c][65] pad
    __shared__ float ps[512];                    // [8][64]
    __shared__ float pq[512];
    __shared__ float mr[64];
    __shared__ float rr[64];
    int qy = blockIdx.x, b = blockIdx.y, z = blockIdx.z;
    const float* in = z ? src : x;
    unsigned short* out = z ? s_sp : q_sp;
    int t = threadIdx.x;
    int qx = t & 63;
    int gq = t >> 6;                   // 0..7
    for (int cc = 0; cc < 32; cc++) {
        int cl = gq + cc * 8;
        const float* rp = in + (((b * 256 + cl) * 256) + 4 * qy) * 256 + 4 * qx;
        float4 r0 = *(const float4*)(rp);
        float4 r1 = *(const float4*)(rp + 256);
        float4 r2 = *(const float4*)(rp + 512);
        float4 r3 = *(const float4*)(rp + 768);
        float m = fmaxf(fmaxf(fmaxf(r0.x, r0.y), fmaxf(r0.z, r0.w)),
                        fmaxf(fmaxf(r1.x, r1.y), fmaxf(r1.z, r1.w)));
        m = fmaxf(m, fmaxf(fmaxf(r2.x, r2.y), fmaxf(r2.z, r2.w)));
        m = fmaxf(m, fmaxf(fmaxf(r3.x, r3.y), fmaxf(r3.z, r3.w)));
        tile[cl * 65 + qx] = m;
    }
    __syncthreads();
    {
        float s = 0.f, q = 0.f;
        for (int i = 0; i < 32; i++) {
            float v = tile[(gq * 32 + i) * 65 + qx];
            s += v; q += v * v;
        }
        ps[gq * 64 + qx] = s;
        pq[gq * 64 + qx] = q;
    }
    __syncthreads();
    if (t < 64) {
        float s = 0.f, q = 0.f;
#pragma unroll
        for (int ww = 0; ww < 8; ww++) { s += ps[ww * 64 + t]; q += pq[ww * 64 + t]; }
        float mean = s * (1.f / 256.f);
        float var = q * (1.f / 256.f) - mean * mean;
        mr[t] = mean; rr[t] = rsqrtf(var + 1e-5f);
    }
    __syncthreads();
    for (int cb4 = 0; cb4 < 4; cb4++) {
#pragma unroll
        for (int kk = 0; kk < 8; kk++) {
            int cl = t & 63;
            int qxx = gq + kk * 8;
            int c = cb4 * 64 + cl;
            float v = tile[c * 65 + qxx];
            out[((b * 64 + qy) * 64 + qxx) * 256 + c] =
                bf16of((v - mr[qxx]) * rr[qxx] * g[c] + bvec[c]);
        }
    }
}

// ---------------- depthwise 3x3 conv + BN(eval) + feature map; 4 ch/thread, u16x4 loads ----------------
__global__ __launch_bounds__(256) void dwconv_k(
    const unsigned short* __restrict__ q_sp, const unsigned short* __restrict__ s_sp,
    const float* __restrict__ qw, const float* __restrict__ qg,
    const float* __restrict__ qb, const float* __restrict__ qm,
    const float* __restrict__ qvar,
    const float* __restrict__ kw, const float* __restrict__ kg,
    const float* __restrict__ kb, const float* __restrict__ km,
    const float* __restrict__ kvar,
    const float* __restrict__ vw, const float* __restrict__ vg,
    const float* __restrict__ vb, const float* __restrict__ vm,
    const float* __restrict__ vvar,
    unsigned short* __restrict__ qf, unsigned short* __restrict__ kf,
    unsigned short* __restrict__ vf) {
    int bid = blockIdx.x;                 // b*1024 + y*16 + xq
    int b = bid >> 10, rem = bid & 1023, y = rem >> 4, xq = rem & 15;
    int t = threadIdx.x;
    int xx = xq * 4 + (t >> 6);           // pixel x
    int c0 = (t & 63) * 4;                // channel quad
    float aq[4] = {0, 0, 0, 0}, ak[4] = {0, 0, 0, 0}, av[4] = {0, 0, 0, 0};
#pragma unroll
    for (int ky = 0; ky < 3; ky++) {
        int yy = y + ky - 1;
        if (yy < 0 || yy > 63) continue;
#pragma unroll
        for (int kx = 0; kx < 3; kx++) {
            int x2 = xx + kx - 1;
            if (x2 < 0 || x2 > 63) continue;
            int off = ((b * 64 + yy) * 64 + x2) * 256 + c0;
            u16x4 qu = *(const u16x4*)(q_sp + off);
            u16x4 su = *(const u16x4*)(s_sp + off);
            int wo = ky * 3 + kx;
#pragma unroll
            for (int i = 0; i < 4; i++) {
                float a = bf2f(qu[i]), s = bf2f(su[i]);
                aq[i] += a * qw[(c0 + i) * 9 + wo];
                ak[i] += s * kw[(c0 + i) * 9 + wo];
                av[i] += s * vw[(c0 + i) * 9 + wo];
            }
        }
    }
    float oq[4], ok[4], ov[4];
#pragma unroll
    for (int i = 0; i < 4; i++) {
        int c = c0 + i;
        float sq = qg[c] * rsqrtf(qvar[c] + 1e-5f);
        float sk = kg[c] * rsqrtf(kvar[c] + 1e-5f);
        float sv = vg[c] * rsqrtf(vvar[c] + 1e-5f);
        float q_ = aq[i] * sq + (qb[c] - qm[c] * sq);
        float k_ = ak[i] * sk + (kb[c] - km[c] * sk);
        ov[i] = av[i] * sv + (vb[c] - vm[c] * sv);
        oq[i] = q_ > 0.f ? q_ + 1.f : expm1f(q_) + 1.f;   // elu + 1
        ok[i] = k_ > 0.f ? k_ + 1.f : expm1f(k_) + 1.f;
    }
    int o = ((b * 64 + y) * 64 + xx) * 256 + c0;
    uint2 u;
    u.x = pk2bf(oq[0], oq[1]); u.y = pk2bf(oq[2], oq[3]); *(uint2*)(qf + o) = u;
    u.x = pk2bf(ok[0], ok[1]); u.y = pk2bf(ok[2], ok[3]); *(uint2*)(kf + o) = u;
    u.x = pk2bf(ov[0], ov[1]); u.y = pk2bf(ov[2], ov[3]); *(uint2*)(vf + o) = u;
}

// ---------------- KV = K^T V (per b,head) + Ksum; bf16 inputs, fp32 accum ----------------
__global__ void kv_part(const unsigned short* __restrict__ kf, const unsigned short* __restrict__ vf,
                        float* __restrict__ kvp, float* __restrict__ kspart) {
    __shared__ float red[4][1024];
    __shared__ float kred[4][32];
    int bid = blockIdx.x;            // bnh*16 + ch
    int bnh = bid >> 4, ch = bid & 15;
    int b = bnh >> 3, nh = bnh & 7;
    int t = threadIdx.x;
    int ls = t >> 6, dkg = (t >> 3) & 7, dvg = t & 7;
    const unsigned short* kb = kf + (size_t)b * 4096 * 256 + nh * 32 + dkg * 4;
    const unsigned short* vb = vf + (size_t)b * 4096 * 256 + nh * 32 + dvg * 4;
    int l0 = ch * 256 + ls * 64;
    float4 a0 = {0,0,0,0}, a1 = a0, a2 = a0, a3 = a0, ks = a0;
    for (int l = l0; l < l0 + 64; l++) {
        u16x4 ku = *(const u16x4*)(kb + (size_t)l * 256);
        u16x4 vu = *(const u16x4*)(vb + (size_t)l * 256);
        float4 k4 = { bf2f(ku[0]), bf2f(ku[1]), bf2f(ku[2]), bf2f(ku[3]) };
        float4 v4 = { bf2f(vu[0]), bf2f(vu[1]), bf2f(vu[2]), bf2f(vu[3]) };
        a0.x += k4.x * v4.x; a0.y += k4.x * v4.y; a0.z += k4.x * v4.z; a0.w += k4.x * v4.w;
        a1.x += k4.y * v4.x; a1.y += k4.y * v4.y; a1.z += k4.y * v4.z; a1.w += k4.y * v4.w;
        a2.x += k4.z * v4.x; a2.y += k4.z * v4.y; a2.z += k4.z * v4.z; a2.w += k4.z * v4.w;
        a3.x += k4.w * v4.x; a3.y += k4.w * v4.y; a3.z += k4.w * v4.z; a3.w += k4.w * v4.w;
        ks.x += k4.x; ks.y += k4.y; ks.z += k4.z; ks.w += k4.w;
    }
    int base = dkg * 128 + dvg * 4;
    *(float4*)(&red[ls][base])      = a0;
    *(float4*)(&red[ls][base + 32]) = a1;
    *(float4*)(&red[ls][base + 64]) = a2;
    *(float4*)(&red[ls][base + 96]) = a3;
    if (dvg == 0) *(float4*)(&kred[ls][dkg * 4]) = ks;
    __syncthreads();
    for (int e = t; e < 1024; e += 256)
        kvp[bid * 1024 + e] = red[0][e] + red[1][e] + red[2][e] + red[3][e];
    if (t < 32) kspart[bid * 32 + t] = kred[0][t] + kred[1][t] + kred[2][t] + kred[3][t];
}

__global__ void kv_red(const float* __restrict__ kvp, const float* __restrict__ kspart,
                       float* __restrict__ kv, float* __restrict__ ksum) {
    int bnh = blockIdx.x;
    int t = threadIdx.x;
    for (int e = t; e < 1024; e += 256) {
        float s = 0.f;
        for (int ch = 0; ch < 16; ch++) s += kvp[(bnh * 16 + ch) * 1024 + e];
        kv[bnh * 1024 + e] = s;
    }
    if (t < 32) {
        float s = 0.f;
        for (int ch = 0; ch < 16; ch++) s += kspart[(bnh * 16 + ch) * 32 + t];
        ksum[bnh * 32 + t] = s;
    }
}

// ---------------- msg = Q*KV*Z, then merge GEMM; bf16 q in, bf16 merged out ----------------
__global__ void msgmerge_k(const unsigned short* __restrict__ qf, const float* __restrict__ kv,
                           const float* __restrict__ ksum, const float* __restrict__ mw,
                           unsigned short* __restrict__ merged) {
    __shared__ float Qs[8 * 256];
    __shared__ float Ms[8 * 256];
    int bid = blockIdx.x;
    int b = bid >> 9, l0 = (bid & 511) * 8;
    int t = threadIdx.x;
#pragma unroll
    for (int tt = 0; tt < 8; tt++) Qs[tt * 256 + t] = bf2f(qf[(b * 4096 + l0 + tt) * 256 + t]);
    __syncthreads();
    int nh = t >> 5, dv = t & 31;
    const float* kvb = kv + (b * 8 + nh) * 1024 + dv;
    const float* ksb = ksum + (b * 8 + nh) * 32;
    float sacc[8] = {0, 0, 0, 0, 0, 0, 0, 0};
    float zacc[8] = {0, 0, 0, 0, 0, 0, 0, 0};
    for (int dk = 0; dk < 32; dk++) {
        float kvv = kvb[dk * 32];
        float ksv = ksb[dk];
#pragma unroll
        for (int tt = 0; tt < 8; tt++) {
            float qv = Qs[tt * 256 + nh * 32 + dk];
            sacc[tt] += qv * kvv;
            zacc[tt] += qv * ksv;
        }
    }
#pragma unroll
    for (int tt = 0; tt < 8; tt++) Ms[tt * 256 + t] = sacc[tt] / (zacc[tt] + 1e-6f);
    __syncthreads();
    float acc8[8] = {0, 0, 0, 0, 0, 0, 0, 0};
    const float* wrow = mw + t * 256;
    for (int c = 0; c < 256; c++) {
        float wv = wrow[c];
#pragma unroll
        for (int tt = 0; tt < 8; tt++) acc8[tt] += Ms[tt * 256 + c] * wv;
    }
#pragma unroll
    for (int tt = 0; tt < 8; tt++) merged[(b * 4096 + l0 + tt) * 256 + t] = bf16of(acc8[tt]);
}

// ---------------- fused: bilinear-up(msg) || cat -> MLP (bf16 MFMA) -> LN2 -> +x ----------------
// R14: R7 plateau structure exactly; merged gather reverted to SCALAR bf16 loads (R13's
// vectorized gather held 4 uint4 + v[8] live -> ~5 dword/thread spill -> WRITE 172MB, +40us).
// At the compiler's fixed 64-arch-reg schedule, every phase must stay at R7's register
// pressure. 1024 thr = 16 waves; 64 px/block; LDS 74KB -> 2 blocks/CU.
__global__ __launch_bounds__(1024) __attribute__((amdgpu_waves_per_eu(4))) void mlp_k(
    const float* __restrict__ x, const unsigned short* __restrict__ merged,
    const uint4* __restrict__ w1img, const uint4* __restrict__ w2img,
    const float* __restrict__ g2, const float* __restrict__ b2,
    float* __restrict__ out) {
    __shared__ __align__(16) char CATB[65536];   // cat[64px][512]bf16 swz; later h1[64px][512]
    __shared__ float ps[1024];                   // [16 waves][64 px]
    __shared__ float pq[1024];
    __shared__ float mr[64];
    __shared__ float rr[64];
    const int t = threadIdx.x;
    const int lane = t & 63;
    const int l15 = lane & 15, l4 = lane >> 4;
    const int w = t >> 6;                        // 0..15
    const int X0 = blockIdx.x * 64;
    const int Y = blockIdx.y;
    const int b = blockIdx.z;

    // ---- build cat tile: x half + bilinear-upsampled msg half ----
    {
        const int p = lane;                      // px column (64)
        const int cg = w;                        // 16 channels per thread-group
#pragma unroll
        for (int it = 0; it < 2; it++) {
            int c0 = cg * 16 + it * 8;
            float v[8];
#pragma unroll
            for (int j = 0; j < 8; j++)
                v[j] = x[((b * 256 + c0 + j) * 256 + Y) * 256 + X0 + p];
            uint4 pk;
            pk.x = pk2bf(v[0], v[1]); pk.y = pk2bf(v[2], v[3]);
            pk.z = pk2bf(v[4], v[5]); pk.w = pk2bf(v[6], v[7]);
            *(uint4*)(CATB + SWZ(p, p * 1024 + c0 * 2)) = pk;
        }
        float sy = (Y - 1.5f) * 0.25f;
        int iy0 = (int)floorf(sy);
        float fy = sy - (float)iy0;
        int y0c = iy0 < 0 ? 0 : iy0;
        int y1c = (iy0 + 1) > 63 ? 63 : (iy0 + 1);
        int X = X0 + p;
        float sx = (X - 1.5f) * 0.25f;
        int ix0 = (int)floorf(sx);
        float fx = sx - (float)ix0;
        int x0c = ix0 < 0 ? 0 : ix0;
        int x1c = (ix0 + 1) > 63 ? 63 : (ix0 + 1);
        float w00 = (1.f - fy) * (1.f - fx), w01 = (1.f - fy) * fx;
        float w10 = fy * (1.f - fx), w11 = fy * fx;
        const unsigned short* m00 = merged + ((b * 64 + y0c) * 64 + x0c) * 256;
        const unsigned short* m01 = merged + ((b * 64 + y0c) * 64 + x1c) * 256;
        const unsigned short* m10 = merged + ((b * 64 + y1c) * 64 + x0c) * 256;
        const unsigned short* m11 = merged + ((b * 64 + y1c) * 64 + x1c) * 256;
#pragma unroll
        for (int it = 0; it < 2; it++) {
            int c0 = cg * 16 + it * 8;
            float v[8];
#pragma unroll
            for (int j = 0; j < 8; j++)
                v[j] = w00 * bf2f(m00[c0 + j]) + w01 * bf2f(m01[c0 + j])
                     + w10 * bf2f(m10[c0 + j]) + w11 * bf2f(m11[c0 + j]);
            uint4 pk;
            pk.x = pk2bf(v[0], v[1]); pk.y = pk2bf(v[2], v[3]);
            pk.z = pk2bf(v[4], v[5]); pk.w = pk2bf(v[6], v[7]);
            *(uint4*)(CATB + SWZ(p, p * 1024 + (256 + c0) * 2)) = pk;
        }
    }
    __syncthreads();

    // ---- GEMM1: 16 rounds BK=32; wave w owns j[w*32..+32); minimal-reg straight loop ----
    f32x4 acc[2][4];
#pragma unroll
    for (int a = 0; a < 2; a++)
#pragma unroll
        for (int n = 0; n < 4; n++) acc[a][n] = (f32x4){0.f, 0.f, 0.f, 0.f};
    {
        const uint4* w1p = w1img + (w * 2) * 64 + lane;   // jt = w*2 + a
        for (int rk = 0; rk < 16; rk++) {
            bf16x8 bf[4];
#pragma unroll
            for (int n = 0; n < 4; n++) {
                int pr = n * 16 + l15;
                bf[n] = *(const bf16x8*)(CATB + SWZ(pr, pr * 1024 + rk * 64 + l4 * 16));
            }
#pragma unroll
            for (int a = 0; a < 2; a++) {
                bf16x8 wa = *(const bf16x8*)(w1p + rk * 2048 + a * 64);
#pragma unroll
                for (int n = 0; n < 4; n++)
                    acc[a][n] = __builtin_amdgcn_mfma_f32_16x16x32_bf16(wa, bf[n], acc[a][n], 0, 0, 0);
            }
        }
    }

    // ---- stash x-residual (bf16 pairs) before h1 overlays CATB ----
    // GEMM2 wave tile: c[w*16..+16) x px[0..64); this thread's c = w*16 + l4*4 + r
    uint2 xs[4];
    {
        int c0 = w * 16 + l4 * 4;
#pragma unroll
        for (int n = 0; n < 4; n++) {
            int px = n * 16 + l15;
            xs[n] = *(const uint2*)(CATB + SWZ(px, px * 1024 + c0 * 2));
        }
    }
    __syncthreads();

    // ---- write relu(h1) into CATB (overlay), rows=px, cols=j ----
#pragma unroll
    for (int a = 0; a < 2; a++) {
        int j0 = w * 32 + a * 16 + l4 * 4;
#pragma unroll
        for (int n = 0; n < 4; n++) {
            int pr = n * 16 + l15;
            uint2 u;
            u.x = pk2bf(fmaxf(acc[a][n][0], 0.f), fmaxf(acc[a][n][1], 0.f));
            u.y = pk2bf(fmaxf(acc[a][n][2], 0.f), fmaxf(acc[a][n][3], 0.f));
            *(uint2*)(CATB + SWZ(pr, pr * 1024 + j0 * 2)) = u;
        }
    }
    __syncthreads();

    // ---- GEMM2: 16 rounds BK=32; wave w owns c[w*16..+16) ----
    f32x4 macc[4];
#pragma unroll
    for (int n = 0; n < 4; n++) macc[n] = (f32x4){0.f, 0.f, 0.f, 0.f};
    {
        const uint4* w2p = w2img + w * 64 + lane;         // ct = w
        for (int rj = 0; rj < 16; rj++) {
            bf16x8 bf[4];
#pragma unroll
            for (int n = 0; n < 4; n++) {
                int pr = n * 16 + l15;
                bf[n] = *(const bf16x8*)(CATB + SWZ(pr, pr * 1024 + rj * 64 + l4 * 16));
            }
            bf16x8 va = *(const bf16x8*)(w2p + rj * 1024);
#pragma unroll
            for (int n = 0; n < 4; n++)
                macc[n] = __builtin_amdgcn_mfma_f32_16x16x32_bf16(va, bf[n], macc[n], 0, 0, 0);
        }
    }

    // ---- epilogue: cross-wave LN over c, residual from stashed bf16(x), store NCHW ----
#pragma unroll
    for (int n = 0; n < 4; n++) {
        float ss = 0.f, qq = 0.f;
#pragma unroll
        for (int r = 0; r < 4; r++) { float vv = macc[n][r]; ss += vv; qq += vv * vv; }
        ss += __shfl_xor(ss, 16); ss += __shfl_xor(ss, 32);
        qq += __shfl_xor(qq, 16); qq += __shfl_xor(qq, 32);
        if (l4 == 0) {
            ps[w * 64 + n * 16 + l15] = ss;
            pq[w * 64 + n * 16 + l15] = qq;
        }
    }
    __syncthreads();
    if (t < 64) {
        float ss = 0.f, qq = 0.f;
#pragma unroll
        for (int ww = 0; ww < 16; ww++) {
            ss += ps[ww * 64 + t];
            qq += pq[ww * 64 + t];
        }
        float mean = ss * (1.f / 256.f);
        float var = qq * (1.f / 256.f) - mean * mean;
        mr[t] = mean; rr[t] = rsqrtf(var + 1e-5f);
    }
    __syncthreads();
    {
        int cbase = w * 16 + l4 * 4;
        float gg[4], bb[4];
#pragma unroll
        for (int r = 0; r < 4; r++) { gg[r] = g2[cbase + r]; bb[r] = b2[cbase + r]; }
#pragma unroll
        for (int n = 0; n < 4; n++) {
            int px = n * 16 + l15;
            uint2 u = xs[n];
            float xr[4];
            xr[0] = bitf(u.x << 16); xr[1] = bitf(u.x & 0xffff0000u);
            xr[2] = bitf(u.y << 16); xr[3] = bitf(u.y & 0xffff0000u);
            float mean = mr[px], rs = rr[px];
#pragma unroll
            for (int r = 0; r < 4; r++) {
                out[((b * 256 + cbase + r) * 256 + Y) * 256 + X0 + px] =
                    xr[r] + (macc[n][r] - mean) * rs * gg[r] + bb[r];
            }
        }
    }
}

extern "C" void kernel_launch(void* const* d_in, const int* in_sizes, int n_in,
                              void* d_out, int out_size, void* d_ws, size_t ws_size,
                              hipStream_t stream) {
    const float* x       = (const float*)d_in[0];
    const float* source  = (const float*)d_in[1];
    const float* ln1_g   = (const float*)d_in[2];
    const float* ln1_b   = (const float*)d_in[3];
    const float* merge_w = (const float*)d_in[4];
    const float* mlp_w1  = (const float*)d_in[5];
    const float* mlp_w2  = (const float*)d_in[6];
    const float* ln2_g   = (const float*)d_in[7];
    const float* ln2_b   = (const float*)d_in[8];
    const float* q_w = (const float*)d_in[9];
    const float* q_bn_g = (const float*)d_in[10];
    const float* q_bn_b = (const float*)d_in[11];
    const float* q_bn_m = (const float*)d_in[12];
    const float* q_bn_v = (const float*)d_in[13];
    const float* k_w = (const float*)d_in[14];
    const float* k_bn_g = (const float*)d_in[15];
    const float* k_bn_b = (const float*)d_in[16];
    const float* k_bn_m = (const float*)d_in[17];
    const float* k_bn_v = (const float*)d_in[18];
    const float* v_w = (const float*)d_in[19];
    const float* v_bn_g = (const float*)d_in[20];
    const float* v_bn_b = (const float*)d_in[21];
    const float* v_bn_m = (const float*)d_in[22];
    const float* v_bn_v = (const float*)d_in[23];
    float* out = (float*)d_out;

    float* ws = (float*)d_ws;
    unsigned short* q_sp   = (unsigned short*)(ws + 0);         // 2,097,152 bf16
    unsigned short* s_sp   = (unsigned short*)(ws + 2097152);   // 2,097,152 bf16
    unsigned short* qf     = (unsigned short*)(ws + 4194304);   // 2,097,152 bf16
    unsigned short* kf     = (unsigned short*)(ws + 6291456);   // 2,097,152 bf16
    unsigned short* vf     = (unsigned short*)(ws + 8388608);   // 2,097,152 bf16
    unsigned short* merged = (unsigned short*)(ws + 10485760);  // 2,097,152 bf16
    float* kvp    = ws + 0;            // overlays q_sp region (dead after dwconv)
    float* kspart = ws + 262144;
    float* kv     = ws + 12650496;     // 16,384
    float* ksum   = ws + 12666880;     // 512
    uint4* w1img  = (uint4*)((char*)d_ws + 50669568);  // 512 KB
    uint4* w2img  = (uint4*)((char*)d_ws + 51193856);  // 256 KB

    build_wimg<<<192, 256, 0, stream>>>(mlp_w1, mlp_w2, w1img, w2img);
    poolln_k<<<dim3(64, 2, 2), 512, 0, stream>>>(x, source, ln1_g, ln1_b, q_sp, s_sp);
    dwconv_k<<<2048, 256, 0, stream>>>(q_sp, s_sp,
                                       q_w, q_bn_g, q_bn_b, q_bn_m, q_bn_v,
                                       k_w, k_bn_g, k_bn_b, k_bn_m, k_bn_v,
                                       v_w, v_bn_g, v_bn_b, v_bn_m, v_bn_v,
                                       qf, kf, vf);
    kv_part<<<256, 256, 0, stream>>>(kf, vf, kvp, kspart);
    kv_red<<<16, 256, 0, stream>>>(kvp, kspart, kv, ksum);
    msgmerge_k<<<1024, 256, 0, stream>>>(qf, kv, ksum, merge_w, merged);
    mlp_k<<<dim3(4, 256, 2), 1024, 0, stream>>>(x, merged, w1img, w2img, ln2_g, ln2_b, out);
}

// Round 15
// 401.989 us; speedup vs baseline: 1.0141x; 1.0141x over previous
//
#include <hip/hip_runtime.h>
#include <hip/hip_bf16.h>
#include <cstdint>

// B=2, C=256, H=W=256, P=4 -> h=w=64, L=4096, NH=8, D=32

typedef __attribute__((ext_vector_type(8))) short bf16x8;
typedef __attribute__((ext_vector_type(4))) float f32x4;
typedef __attribute__((ext_vector_type(4))) unsigned short u16x4;

#define SWZ(p, off) ((off) ^ (((p) & 7) << 4))

__device__ inline unsigned pk2bf(float a, float b) {
    unsigned ua = __builtin_bit_cast(unsigned, a);
    ua += 0x7fffu + ((ua >> 16) & 1u);
    unsigned ub = __builtin_bit_cast(unsigned, b);
    ub += 0x7fffu + ((ub >> 16) & 1u);
    return (ua >> 16) | (ub & 0xffff0000u);
}
__device__ inline unsigned short bf16of(float a) {
    unsigned ua = __builtin_bit_cast(unsigned, a);
    ua += 0x7fffu + ((ua >> 16) & 1u);
    return (unsigned short)(ua >> 16);
}
__device__ inline float bitf(unsigned u) { return __builtin_bit_cast(float, u); }
__device__ inline float bf2f(unsigned short u) { return bitf(((unsigned)u) << 16); }

// ---------------- W image packer: MFMA A-fragment order, bf16 ----------------
// W1 image: [16 rk][32 jt][64 lane] uint4 ; lane l = W1[j=jt*16+(l&15)][k=rk*32+8*(l>>4)..+7]
// W2 image: [16 rj][16 ct][64 lane] uint4 ; lane l = W2[c=ct*16+(l&15)][j=rj*32+8*(l>>4)..+7]
__global__ void build_wimg(const float* __restrict__ w1, const float* __restrict__ w2,
                           uint4* __restrict__ w1img, uint4* __restrict__ w2img) {
    int idx = blockIdx.x * 256 + threadIdx.x;
    if (idx < 32768) {
        int rk = idx >> 11, jt = (idx >> 6) & 31, l = idx & 63;
        int j = jt * 16 + (l & 15);
        int k0 = rk * 32 + 8 * (l >> 4);
        const float* s = w1 + j * 512 + k0;
        uint4 pk;
        pk.x = pk2bf(s[0], s[1]); pk.y = pk2bf(s[2], s[3]);
        pk.z = pk2bf(s[4], s[5]); pk.w = pk2bf(s[6], s[7]);
        w1img[idx] = pk;
    } else {
        int id2 = idx - 32768;  // < 16384
        int rj = id2 >> 10, ct = (id2 >> 6) & 15, l = id2 & 63;
        int c = ct * 16 + (l & 15);
        int j0 = rj * 32 + 8 * (l >> 4);
        const float* s = w2 + c * 512 + j0;
        uint4 pk;
        pk.x = pk2bf(s[0], s[1]); pk.y = pk2bf(s[2], s[3]);
        pk.z = pk2bf(s[4], s[5]); pk.w = pk2bf(s[6], s[7]);
        w2img[id2] = pk;
    }
}

// ---------------- fused maxpool 4x4 + LayerNorm -> NHWC bf16 [b][qy][qx][c] ----------------
__global__ __launch_bounds__(512) void poolln_k(
    const float* __restrict__ x, const float* __restrict__ src,
    const float* __restrict__ g, const float* __restrict__ bvec,
    unsigned short* __restrict__ q_sp, unsigned short* __restrict__ s_sp) {
    __shared__ __align__(16) float tile[16640];  // [256 c][65] pad
    __shared__ float ps[512];                    // [8][64]
    __shared__ float pq[512];
    __shared__ float mr[64];
    __shared__ float rr[64];
    int qy = blockIdx.x, b = blockIdx.y, z = blockIdx.z;
    const float* in = z ? src : x;
    unsigned short* out = z ? s_sp : q_sp;
    int t = threadIdx.x;
    int qx = t & 63;
    int gq = t >> 6;                   // 0..7
    for (int cc = 0; cc < 32; cc++) {
        int cl = gq + cc * 8;
        const float* rp = in + (((b * 256 + cl) * 256) + 4 * qy) * 256 + 4 * qx;
        float4 r0 = *(const float4*)(rp);
        float4 r1 = *(const float4*)(rp + 256);
        float4 r2 = *(const float4*)(rp + 512);
        float4 r3 = *(const float4*)(rp + 768);
        float m = fmaxf(fmaxf(fmaxf(r0.x, r0.y), fmaxf(r0.z, r0.w)),
                        fmaxf(fmaxf(r1.x, r1.y), fmaxf(r1.z, r1.w)));
        m = fmaxf(m, fmaxf(fmaxf(r2.x, r2.y), fmaxf(r2.z, r2.w)));
        m = fmaxf(m, fmaxf(fmaxf(r3.x, r3.y), fmaxf(r3.z, r3.w)));
        tile[cl * 65 + qx] = m;
    }
    __syncthreads();
    {
        float s = 0.f, q = 0.f;
        for (int i = 0; i < 32; i++) {
            float v = tile[(gq * 32 + i) * 65 + qx];
            s += v; q += v * v;
        }
        ps[gq * 64 + qx] = s;
        pq[gq * 64 + qx] = q;
    }
    __syncthreads();
    if (t < 64) {
        float s = 0.f, q = 0.f;
#pragma unroll
        for (int ww = 0; ww < 8; ww++) { s += ps[ww * 64 + t]; q += pq[ww * 64 + t]; }
        float mean = s * (1.f / 256.f);
        float var = q * (1.f / 256.f) - mean * mean;
        mr[t] = mean; rr[t] = rsqrtf(var + 1e-5f);
    }
    __syncthreads();
    for (int cb4 = 0; cb4 < 4; cb4++) {
#pragma unroll
        for (int kk = 0; kk < 8; kk++) {
            int cl = t & 63;
            int qxx = gq + kk * 8;
            int c = cb4 * 64 + cl;
            float v = tile[c * 65 + qxx];
            out[((b * 64 + qy) * 64 + qxx) * 256 + c] =
                bf16of((v - mr[qxx]) * rr[qxx] * g[c] + bvec[c]);
        }
    }
}

// ---------------- depthwise 3x3 conv + BN(eval) + feature map; bf16 in/out (R13 form) ----------------
__global__ void dwconv_k(const unsigned short* __restrict__ q_sp, const unsigned short* __restrict__ s_sp,
                         const float* __restrict__ qw, const float* __restrict__ qg,
                         const float* __restrict__ qb, const float* __restrict__ qm,
                         const float* __restrict__ qvar,
                         const float* __restrict__ kw, const float* __restrict__ kg,
                         const float* __restrict__ kb, const float* __restrict__ km,
                         const float* __restrict__ kvar,
                         const float* __restrict__ vw, const float* __restrict__ vg,
                         const float* __restrict__ vb, const float* __restrict__ vm,
                         const float* __restrict__ vvar,
                         unsigned short* __restrict__ qf, unsigned short* __restrict__ kf,
                         unsigned short* __restrict__ vf) {
    int bid = blockIdx.x;
    int b = bid >> 12, l = bid & 4095, y = l >> 6, xx = l & 63;
    int c = threadIdx.x;
    float aq = 0.f, ak = 0.f, av = 0.f;
#pragma unroll
    for (int ky = 0; ky < 3; ky++) {
        int yy = y + ky - 1;
        if (yy < 0 || yy > 63) continue;
#pragma unroll
        for (int kx = 0; kx < 3; kx++) {
            int x2 = xx + kx - 1;
            if (x2 < 0 || x2 > 63) continue;
            int off = ((b * 64 + yy) * 64 + x2) * 256 + c;
            float a = bf2f(q_sp[off]), s = bf2f(s_sp[off]);
            aq += a * qw[c * 9 + ky * 3 + kx];
            ak += s * kw[c * 9 + ky * 3 + kx];
            av += s * vw[c * 9 + ky * 3 + kx];
        }
    }
    float sq = qg[c] * rsqrtf(qvar[c] + 1e-5f);
    float sk = kg[c] * rsqrtf(kvar[c] + 1e-5f);
    float sv = vg[c] * rsqrtf(vvar[c] + 1e-5f);
    float oq = aq * sq + (qb[c] - qm[c] * sq);
    float ok = ak * sk + (kb[c] - km[c] * sk);
    float ov = av * sv + (vb[c] - vm[c] * sv);
    oq = oq > 0.f ? oq + 1.f : expm1f(oq) + 1.f;   // elu + 1
    ok = ok > 0.f ? ok + 1.f : expm1f(ok) + 1.f;
    int o = (b * 4096 + l) * 256 + c;
    qf[o] = bf16of(oq); kf[o] = bf16of(ok); vf[o] = bf16of(ov);
}

// ---------------- KV = K^T V (per b,head) + Ksum; bf16 inputs, fp32 accum ----------------
__global__ void kv_part(const unsigned short* __restrict__ kf, const unsigned short* __restrict__ vf,
                        float* __restrict__ kvp, float* __restrict__ kspart) {
    __shared__ float red[4][1024];
    __shared__ float kred[4][32];
    int bid = blockIdx.x;            // bnh*16 + ch
    int bnh = bid >> 4, ch = bid & 15;
    int b = bnh >> 3, nh = bnh & 7;
    int t = threadIdx.x;
    int ls = t >> 6, dkg = (t >> 3) & 7, dvg = t & 7;
    const unsigned short* kb = kf + (size_t)b * 4096 * 256 + nh * 32 + dkg * 4;
    const unsigned short* vb = vf + (size_t)b * 4096 * 256 + nh * 32 + dvg * 4;
    int l0 = ch * 256 + ls * 64;
    float4 a0 = {0,0,0,0}, a1 = a0, a2 = a0, a3 = a0, ks = a0;
    for (int l = l0; l < l0 + 64; l++) {
        u16x4 ku = *(const u16x4*)(kb + (size_t)l * 256);
        u16x4 vu = *(const u16x4*)(vb + (size_t)l * 256);
        float4 k4 = { bf2f(ku[0]), bf2f(ku[1]), bf2f(ku[2]), bf2f(ku[3]) };
        float4 v4 = { bf2f(vu[0]), bf2f(vu[1]), bf2f(vu[2]), bf2f(vu[3]) };
        a0.x += k4.x * v4.x; a0.y += k4.x * v4.y; a0.z += k4.x * v4.z; a0.w += k4.x * v4.w;
        a1.x += k4.y * v4.x; a1.y += k4.y * v4.y; a1.z += k4.y * v4.z; a1.w += k4.y * v4.w;
        a2.x += k4.z * v4.x; a2.y += k4.z * v4.y; a2.z += k4.z * v4.z; a2.w += k4.z * v4.w;
        a3.x += k4.w * v4.x; a3.y += k4.w * v4.y; a3.z += k4.w * v4.z; a3.w += k4.w * v4.w;
        ks.x += k4.x; ks.y += k4.y; ks.z += k4.z; ks.w += k4.w;
    }
    int base = dkg * 128 + dvg * 4;
    *(float4*)(&red[ls][base])      = a0;
    *(float4*)(&red[ls][base + 32]) = a1;
    *(float4*)(&red[ls][base + 64]) = a2;
    *(float4*)(&red[ls][base + 96]) = a3;
    if (dvg == 0) *(float4*)(&kred[ls][dkg * 4]) = ks;
    __syncthreads();
    for (int e = t; e < 1024; e += 256)
        kvp[bid * 1024 + e] = red[0][e] + red[1][e] + red[2][e] + red[3][e];
    if (t < 32) kspart[bid * 32 + t] = kred[0][t] + kred[1][t] + kred[2][t] + kred[3][t];
}

__global__ void kv_red(const float* __restrict__ kvp, const float* __restrict__ kspart,
                       float* __restrict__ kv, float* __restrict__ ksum) {
    int bnh = blockIdx.x;
    int t = threadIdx.x;
    for (int e = t; e < 1024; e += 256) {
        float s = 0.f;
        for (int ch = 0; ch < 16; ch++) s += kvp[(bnh * 16 + ch) * 1024 + e];
        kv[bnh * 1024 + e] = s;
    }
    if (t < 32) {
        float s = 0.f;
        for (int ch = 0; ch < 16; ch++) s += kspart[(bnh * 16 + ch) * 32 + t];
        ksum[bnh * 32 + t] = s;
    }
}

// ---------------- msg = Q*KV*Z, then merge GEMM; bf16 q in, f32 merged out ----------------
__global__ void msgmerge_k(const unsigned short* __restrict__ qf, const float* __restrict__ kv,
                           const float* __restrict__ ksum, const float* __restrict__ mw,
                           float* __restrict__ merged) {
    __shared__ float Qs[8 * 256];
    __shared__ float Ms[8 * 256];
    int bid = blockIdx.x;
    int b = bid >> 9, l0 = (bid & 511) * 8;
    int t = threadIdx.x;
#pragma unroll
    for (int tt = 0; tt < 8; tt++) Qs[tt * 256 + t] = bf2f(qf[(b * 4096 + l0 + tt) * 256 + t]);
    __syncthreads();
    int nh = t >> 5, dv = t & 31;
    const float* kvb = kv + (b * 8 + nh) * 1024 + dv;
    const float* ksb = ksum + (b * 8 + nh) * 32;
    float sacc[8] = {0, 0, 0, 0, 0, 0, 0, 0};
    float zacc[8] = {0, 0, 0, 0, 0, 0, 0, 0};
    for (int dk = 0; dk < 32; dk++) {
        float kvv = kvb[dk * 32];
        float ksv = ksb[dk];
#pragma unroll
        for (int tt = 0; tt < 8; tt++) {
            float qv = Qs[tt * 256 + nh * 32 + dk];
            sacc[tt] += qv * kvv;
            zacc[tt] += qv * ksv;
        }
    }
#pragma unroll
    for (int tt = 0; tt < 8; tt++) Ms[tt * 256 + t] = sacc[tt] / (zacc[tt] + 1e-6f);
    __syncthreads();
    float acc8[8] = {0, 0, 0, 0, 0, 0, 0, 0};
    const float* wrow = mw + t * 256;
    for (int c = 0; c < 256; c++) {
        float wv = wrow[c];
#pragma unroll
        for (int tt = 0; tt < 8; tt++) acc8[tt] += Ms[tt * 256 + c] * wv;
    }
#pragma unroll
    for (int tt = 0; tt < 8; tt++) merged[(b * 4096 + l0 + tt) * 256 + t] = acc8[tt];
}

// ---------------- fused: bilinear-up(msg) || cat -> MLP (bf16 MFMA) -> LN2 -> +x ----------------
// R15: EXACT R7 mlp_k (verified 181us / WRITE 131MB). merged stays f32: every bf16-merged
// variant (R13 vectorized, R14 scalar-but-autovectorized) spilled ~57MB at the pinned
// 64-arch-reg schedule. Do not touch the cat-build phase.
// 1024 thr = 16 waves; 64 px/block; LDS 74KB -> 2 blocks/CU.
__global__ __launch_bounds__(1024) __attribute__((amdgpu_waves_per_eu(4))) void mlp_k(
    const float* __restrict__ x, const float* __restrict__ merged,
    const uint4* __restrict__ w1img, const uint4* __restrict__ w2img,
    const float* __restrict__ g2, const float* __restrict__ b2,
    float* __restrict__ out) {
    __shared__ __align__(16) char CATB[65536];   // cat[64px][512]bf16 swz; later h1[64px][512]
    __shared__ float ps[1024];                   // [16 waves][64 px]
    __shared__ float pq[1024];
    __shared__ float mr[64];
    __shared__ float rr[64];
    const int t = threadIdx.x;
    const int lane = t & 63;
    const int l15 = lane & 15, l4 = lane >> 4;
    const int w = t >> 6;                        // 0..15
    const int X0 = blockIdx.x * 64;
    const int Y = blockIdx.y;
    const int b = blockIdx.z;

    // ---- build cat tile: x half + bilinear-upsampled msg half ----
    {
        const int p = lane;                      // px column (64)
        const int cg = w;                        // 16 channels per thread-group
#pragma unroll
        for (int it = 0; it < 2; it++) {
            int c0 = cg * 16 + it * 8;
            float v[8];
#pragma unroll
            for (int j = 0; j < 8; j++)
                v[j] = x[((b * 256 + c0 + j) * 256 + Y) * 256 + X0 + p];
            uint4 pk;
            pk.x = pk2bf(v[0], v[1]); pk.y = pk2bf(v[2], v[3]);
            pk.z = pk2bf(v[4], v[5]); pk.w = pk2bf(v[6], v[7]);
            *(uint4*)(CATB + SWZ(p, p * 1024 + c0 * 2)) = pk;
        }
        float sy = (Y - 1.5f) * 0.25f;
        int iy0 = (int)floorf(sy);
        float fy = sy - (float)iy0;
        int y0c = iy0 < 0 ? 0 : iy0;
        int y1c = (iy0 + 1) > 63 ? 63 : (iy0 + 1);
        int X = X0 + p;
        float sx = (X - 1.5f) * 0.25f;
        int ix0 = (int)floorf(sx);
        float fx = sx - (float)ix0;
        int x0c = ix0 < 0 ? 0 : ix0;
        int x1c = (ix0 + 1) > 63 ? 63 : (ix0 + 1);
        float w00 = (1.f - fy) * (1.f - fx), w01 = (1.f - fy) * fx;
        float w10 = fy * (1.f - fx), w11 = fy * fx;
        const float* m00 = merged + ((b * 64 + y0c) * 64 + x0c) * 256;
        const float* m01 = merged + ((b * 64 + y0c) * 64 + x1c) * 256;
        const float* m10 = merged + ((b * 64 + y1c) * 64 + x0c) * 256;
        const float* m11 = merged + ((b * 64 + y1c) * 64 + x1c) * 256;
#pragma unroll
        for (int it = 0; it < 2; it++) {
            int c0 = cg * 16 + it * 8;
            float v[8];
#pragma unroll
            for (int j = 0; j < 8; j++)
                v[j] = w00 * m00[c0 + j] + w01 * m01[c0 + j] + w10 * m10[c0 + j] + w11 * m11[c0 + j];
            uint4 pk;
            pk.x = pk2bf(v[0], v[1]); pk.y = pk2bf(v[2], v[3]);
            pk.z = pk2bf(v[4], v[5]); pk.w = pk2bf(v[6], v[7]);
            *(uint4*)(CATB + SWZ(p, p * 1024 + (256 + c0) * 2)) = pk;
        }
    }
    __syncthreads();

    // ---- GEMM1: 16 rounds BK=32; wave w owns j[w*32..+32); minimal-reg straight loop ----
    f32x4 acc[2][4];
#pragma unroll
    for (int a = 0; a < 2; a++)
#pragma unroll
        for (int n = 0; n < 4; n++) acc[a][n] = (f32x4){0.f, 0.f, 0.f, 0.f};
    {
        const uint4* w1p = w1img + (w * 2) * 64 + lane;   // jt = w*2 + a
        for (int rk = 0; rk < 16; rk++) {
            bf16x8 bf[4];
#pragma unroll
            for (int n = 0; n < 4; n++) {
                int pr = n * 16 + l15;
                bf[n] = *(const bf16x8*)(CATB + SWZ(pr, pr * 1024 + rk * 64 + l4 * 16));
            }
#pragma unroll
            for (int a = 0; a < 2; a++) {
                bf16x8 wa = *(const bf16x8*)(w1p + rk * 2048 + a * 64);
#pragma unroll
                for (int n = 0; n < 4; n++)
                    acc[a][n] = __builtin_amdgcn_mfma_f32_16x16x32_bf16(wa, bf[n], acc[a][n], 0, 0, 0);
            }
        }
    }

    // ---- stash x-residual (bf16 pairs) before h1 overlays CATB ----
    // GEMM2 wave tile: c[w*16..+16) x px[0..64); this thread's c = w*16 + l4*4 + r
    uint2 xs[4];
    {
        int c0 = w * 16 + l4 * 4;
#pragma unroll
        for (int n = 0; n < 4; n++) {
            int px = n * 16 + l15;
            xs[n] = *(const uint2*)(CATB + SWZ(px, px * 1024 + c0 * 2));
        }
    }
    __syncthreads();

    // ---- write relu(h1) into CATB (overlay), rows=px, cols=j ----
#pragma unroll
    for (int a = 0; a < 2; a++) {
        int j0 = w * 32 + a * 16 + l4 * 4;
#pragma unroll
        for (int n = 0; n < 4; n++) {
            int pr = n * 16 + l15;
            uint2 u;
            u.x = pk2bf(fmaxf(acc[a][n][0], 0.f), fmaxf(acc[a][n][1], 0.f));
            u.y = pk2bf(fmaxf(acc[a][n][2], 0.f), fmaxf(acc[a][n][3], 0.f));
            *(uint2*)(CATB + SWZ(pr, pr * 1024 + j0 * 2)) = u;
        }
    }
    __syncthreads();

    // ---- GEMM2: 16 rounds BK=32; wave w owns c[w*16..+16) ----
    f32x4 macc[4];
#pragma unroll
    for (int n = 0; n < 4; n++) macc[n] = (f32x4){0.f, 0.f, 0.f, 0.f};
    {
        const uint4* w2p = w2img + w * 64 + lane;         // ct = w
        for (int rj = 0; rj < 16; rj++) {
            bf16x8 bf[4];
#pragma unroll
            for (int n = 0; n < 4; n++) {
                int pr = n * 16 + l15;
                bf[n] = *(const bf16x8*)(CATB + SWZ(pr, pr * 1024 + rj * 64 + l4 * 16));
            }
            bf16x8 va = *(const bf16x8*)(w2p + rj * 1024);
#pragma unroll
            for (int n = 0; n < 4; n++)
                macc[n] = __builtin_amdgcn_mfma_f32_16x16x32_bf16(va, bf[n], macc[n], 0, 0, 0);
        }
    }

    // ---- epilogue: cross-wave LN over c, residual from stashed bf16(x), store NCHW ----
#pragma unroll
    for (int n = 0; n < 4; n++) {
        float ss = 0.f, qq = 0.f;
#pragma unroll
        for (int r = 0; r < 4; r++) { float vv = macc[n][r]; ss += vv; qq += vv * vv; }
        ss += __shfl_xor(ss, 16); ss += __shfl_xor(ss, 32);
        qq += __shfl_xor(qq, 16); qq += __shfl_xor(qq, 32);
        if (l4 == 0) {
            ps[w * 64 + n * 16 + l15] = ss;
            pq[w * 64 + n * 16 + l15] = qq;
        }
    }
    __syncthreads();
    if (t < 64) {
        float ss = 0.f, qq = 0.f;
#pragma unroll
        for (int ww = 0; ww < 16; ww++) {
            ss += ps[ww * 64 + t];
            qq += pq[ww * 64 + t];
        }
        float mean = ss * (1.f / 256.f);
        float var = qq * (1.f / 256.f) - mean * mean;
        mr[t] = mean; rr[t] = rsqrtf(var + 1e-5f);
    }
    __syncthreads();
    {
        int cbase = w * 16 + l4 * 4;
        float gg[4], bb[4];
#pragma unroll
        for (int r = 0; r < 4; r++) { gg[r] = g2[cbase + r]; bb[r] = b2[cbase + r]; }
#pragma unroll
        for (int n = 0; n < 4; n++) {
            int px = n * 16 + l15;
            uint2 u = xs[n];
            float xr[4];
            xr[0] = bitf(u.x << 16); xr[1] = bitf(u.x & 0xffff0000u);
            xr[2] = bitf(u.y << 16); xr[3] = bitf(u.y & 0xffff0000u);
            float mean = mr[px], rs = rr[px];
#pragma unroll
            for (int r = 0; r < 4; r++) {
                out[((b * 256 + cbase + r) * 256 + Y) * 256 + X0 + px] =
                    xr[r] + (macc[n][r] - mean) * rs * gg[r] + bb[r];
            }
        }
    }
}

extern "C" void kernel_launch(void* const* d_in, const int* in_sizes, int n_in,
                              void* d_out, int out_size, void* d_ws, size_t ws_size,
                              hipStream_t stream) {
    const float* x       = (const float*)d_in[0];
    const float* source  = (const float*)d_in[1];
    const float* ln1_g   = (const float*)d_in[2];
    const float* ln1_b   = (const float*)d_in[3];
    const float* merge_w = (const float*)d_in[4];
    const float* mlp_w1  = (const float*)d_in[5];
    const float* mlp_w2  = (const float*)d_in[6];
    const float* ln2_g   = (const float*)d_in[7];
    const float* ln2_b   = (const float*)d_in[8];
    const float* q_w = (const float*)d_in[9];
    const float* q_bn_g = (const float*)d_in[10];
    const float* q_bn_b = (const float*)d_in[11];
    const float* q_bn_m = (const float*)d_in[12];
    const float* q_bn_v = (const float*)d_in[13];
    const float* k_w = (const float*)d_in[14];
    const float* k_bn_g = (const float*)d_in[15];
    const float* k_bn_b = (const float*)d_in[16];
    const float* k_bn_m = (const float*)d_in[17];
    const float* k_bn_v = (const float*)d_in[18];
    const float* v_w = (const float*)d_in[19];
    const float* v_bn_g = (const float*)d_in[20];
    const float* v_bn_b = (const float*)d_in[21];
    const float* v_bn_m = (const float*)d_in[22];
    const float* v_bn_v = (const float*)d_in[23];
    float* out = (float*)d_out;

    float* ws = (float*)d_ws;
    unsigned short* q_sp   = (unsigned short*)(ws + 0);         // 2,097,152 bf16
    unsigned short* s_sp   = (unsigned short*)(ws + 2097152);   // 2,097,152 bf16
    unsigned short* qf     = (unsigned short*)(ws + 4194304);   // 2,097,152 bf16
    unsigned short* kf     = (unsigned short*)(ws + 6291456);   // 2,097,152 bf16
    unsigned short* vf     = (unsigned short*)(ws + 8388608);   // 2,097,152 bf16
    float* merged = ws + 10485760;     // 2,097,152 f32
    float* kvp    = ws + 0;            // overlays q_sp region (dead after dwconv)
    float* kspart = ws + 262144;
    float* kv     = ws + 12650496;     // 16,384
    float* ksum   = ws + 12666880;     // 512
    uint4* w1img  = (uint4*)((char*)d_ws + 50669568);  // 512 KB
    uint4* w2img  = (uint4*)((char*)d_ws + 51193856);  // 256 KB

    build_wimg<<<192, 256, 0, stream>>>(mlp_w1, mlp_w2, w1img, w2img);
    poolln_k<<<dim3(64, 2, 2), 512, 0, stream>>>(x, source, ln1_g, ln1_b, q_sp, s_sp);
    dwconv_k<<<8192, 256, 0, stream>>>(q_sp, s_sp,
                                       q_w, q_bn_g, q_bn_b, q_bn_m, q_bn_v,
                                       k_w, k_bn_g, k_bn_b, k_bn_m, k_bn_v,
                                       v_w, v_bn_g, v_bn_b, v_bn_m, v_bn_v,
                                       qf, kf, vf);
    kv_part<<<256, 256, 0, stream>>>(kf, vf, kvp, kspart);
    kv_red<<<16, 256, 0, stream>>>(kvp, kspart, kv, ksum);
    msgmerge_k<<<1024, 256, 0, stream>>>(qf, kv, ksum, merge_w, merged);
    mlp_k<<<dim3(4, 256, 2), 1024, 0, stream>>>(x, merged, w1img, w2img, ln2_g, ln2_b, out);
}

// Round 16
// 335.852 us; speedup vs baseline: 1.2138x; 1.1969x over previous
//
#include <hip/hip_runtime.h>
#include <hip/hip_bf16.h>
#include <cstdint>

// B=2, C=256, H=W=256, P=4 -> h=w=64, L=4096, NH=8, D=32
// R16 = EXACT Round-8 build (best verified: 336.1us total; mlp_k 180us, WRITE 131MB).
// Rationale: mlp_k's codegen is balanced at the 64-arch-reg edge; ANY sibling-kernel
// change in this TU (e.g. bf16 aux helpers, R13-R15) perturbs regalloc and flips it
// into ~65MB scratch spill (+40-70us). f32 aux builds never spill (R7/R8/R11).

typedef __attribute__((ext_vector_type(8))) short bf16x8;
typedef __attribute__((ext_vector_type(4))) float f32x4;

#define SWZ(p, off) ((off) ^ (((p) & 7) << 4))

__device__ inline unsigned pk2bf(float a, float b) {
    unsigned ua = __builtin_bit_cast(unsigned, a);
    ua += 0x7fffu + ((ua >> 16) & 1u);
    unsigned ub = __builtin_bit_cast(unsigned, b);
    ub += 0x7fffu + ((ub >> 16) & 1u);
    return (ua >> 16) | (ub & 0xffff0000u);
}
__device__ inline float bitf(unsigned u) { return __builtin_bit_cast(float, u); }

// ---------------- W image packer: MFMA A-fragment order, bf16 ----------------
// W1 image: [16 rk][32 jt][64 lane] uint4 ; lane l = W1[j=jt*16+(l&15)][k=rk*32+8*(l>>4)..+7]
// W2 image: [16 rj][16 ct][64 lane] uint4 ; lane l = W2[c=ct*16+(l&15)][j=rj*32+8*(l>>4)..+7]
__global__ void build_wimg(const float* __restrict__ w1, const float* __restrict__ w2,
                           uint4* __restrict__ w1img, uint4* __restrict__ w2img) {
    int idx = blockIdx.x * 256 + threadIdx.x;
    if (idx < 32768) {
        int rk = idx >> 11, jt = (idx >> 6) & 31, l = idx & 63;
        int j = jt * 16 + (l & 15);
        int k0 = rk * 32 + 8 * (l >> 4);
        const float* s = w1 + j * 512 + k0;
        uint4 pk;
        pk.x = pk2bf(s[0], s[1]); pk.y = pk2bf(s[2], s[3]);
        pk.z = pk2bf(s[4], s[5]); pk.w = pk2bf(s[6], s[7]);
        w1img[idx] = pk;
    } else {
        int id2 = idx - 32768;  // < 16384
        int rj = id2 >> 10, ct = (id2 >> 6) & 15, l = id2 & 63;
        int c = ct * 16 + (l & 15);
        int j0 = rj * 32 + 8 * (l >> 4);
        const float* s = w2 + c * 512 + j0;
        uint4 pk;
        pk.x = pk2bf(s[0], s[1]); pk.y = pk2bf(s[2], s[3]);
        pk.z = pk2bf(s[4], s[5]); pk.w = pk2bf(s[6], s[7]);
        w2img[id2] = pk;
    }
}

// ---------------- fused maxpool 4x4 + LayerNorm -> NHWC [b][qy][qx][c] ----------------
__global__ __launch_bounds__(512) void poolln_k(
    const float* __restrict__ x, const float* __restrict__ src,
    const float* __restrict__ g, const float* __restrict__ bvec,
    float* __restrict__ q_sp, float* __restrict__ s_sp) {
    __shared__ __align__(16) float tile[16640];  // [256 c][65] pad
    __shared__ float ps[512];                    // [8][64]
    __shared__ float pq[512];
    __shared__ float mr[64];
    __shared__ float rr[64];
    int qy = blockIdx.x, b = blockIdx.y, z = blockIdx.z;
    const float* in = z ? src : x;
    float* out = z ? s_sp : q_sp;
    int t = threadIdx.x;
    int qx = t & 63;
    int gq = t >> 6;                   // 0..7
    for (int cc = 0; cc < 32; cc++) {
        int cl = gq + cc * 8;
        const float* rp = in + (((b * 256 + cl) * 256) + 4 * qy) * 256 + 4 * qx;
        float4 r0 = *(const float4*)(rp);
        float4 r1 = *(const float4*)(rp + 256);
        float4 r2 = *(const float4*)(rp + 512);
        float4 r3 = *(const float4*)(rp + 768);
        float m = fmaxf(fmaxf(fmaxf(r0.x, r0.y), fmaxf(r0.z, r0.w)),
                        fmaxf(fmaxf(r1.x, r1.y), fmaxf(r1.z, r1.w)));
        m = fmaxf(m, fmaxf(fmaxf(r2.x, r2.y), fmaxf(r2.z, r2.w)));
        m = fmaxf(m, fmaxf(fmaxf(r3.x, r3.y), fmaxf(r3.z, r3.w)));
        tile[cl * 65 + qx] = m;
    }
    __syncthreads();
    {
        float s = 0.f, q = 0.f;
        for (int i = 0; i < 32; i++) {
            float v = tile[(gq * 32 + i) * 65 + qx];
            s += v; q += v * v;
        }
        ps[gq * 64 + qx] = s;
        pq[gq * 64 + qx] = q;
    }
    __syncthreads();
    if (t < 64) {
        float s = 0.f, q = 0.f;
#pragma unroll
        for (int ww = 0; ww < 8; ww++) { s += ps[ww * 64 + t]; q += pq[ww * 64 + t]; }
        float mean = s * (1.f / 256.f);
        float var = q * (1.f / 256.f) - mean * mean;
        mr[t] = mean; rr[t] = rsqrtf(var + 1e-5f);
    }
    __syncthreads();
    for (int cb4 = 0; cb4 < 4; cb4++) {
#pragma unroll
        for (int kk = 0; kk < 8; kk++) {
            int cl = t & 63;
            int qxx = gq + kk * 8;
            int c = cb4 * 64 + cl;
            float v = tile[c * 65 + qxx];
            out[((b * 64 + qy) * 64 + qxx) * 256 + c] =
                (v - mr[qxx]) * rr[qxx] * g[c] + bvec[c];
        }
    }
}

// ---------------- depthwise 3x3 conv + BN(eval) + feature map ----------------
__global__ void dwconv_k(const float* __restrict__ q_sp, const float* __restrict__ s_sp,
                         const float* __restrict__ qw, const float* __restrict__ qg,
                         const float* __restrict__ qb, const float* __restrict__ qm,
                         const float* __restrict__ qvar,
                         const float* __restrict__ kw, const float* __restrict__ kg,
                         const float* __restrict__ kb, const float* __restrict__ km,
                         const float* __restrict__ kvar,
                         const float* __restrict__ vw, const float* __restrict__ vg,
                         const float* __restrict__ vb, const float* __restrict__ vm,
                         const float* __restrict__ vvar,
                         float* __restrict__ qf, float* __restrict__ kf, float* __restrict__ vf) {
    int bid = blockIdx.x;
    int b = bid >> 12, l = bid & 4095, y = l >> 6, xx = l & 63;
    int c = threadIdx.x;
    float aq = 0.f, ak = 0.f, av = 0.f;
#pragma unroll
    for (int ky = 0; ky < 3; ky++) {
        int yy = y + ky - 1;
        if (yy < 0 || yy > 63) continue;
#pragma unroll
        for (int kx = 0; kx < 3; kx++) {
            int x2 = xx + kx - 1;
            if (x2 < 0 || x2 > 63) continue;
            int off = ((b * 64 + yy) * 64 + x2) * 256 + c;
            float a = q_sp[off], s = s_sp[off];
            aq += a * qw[c * 9 + ky * 3 + kx];
            ak += s * kw[c * 9 + ky * 3 + kx];
            av += s * vw[c * 9 + ky * 3 + kx];
        }
    }
    float sq = qg[c] * rsqrtf(qvar[c] + 1e-5f);
    float sk = kg[c] * rsqrtf(kvar[c] + 1e-5f);
    float sv = vg[c] * rsqrtf(vvar[c] + 1e-5f);
    float oq = aq * sq + (qb[c] - qm[c] * sq);
    float ok = ak * sk + (kb[c] - km[c] * sk);
    float ov = av * sv + (vb[c] - vm[c] * sv);
    oq = oq > 0.f ? oq + 1.f : expm1f(oq) + 1.f;   // elu + 1
    ok = ok > 0.f ? ok + 1.f : expm1f(ok) + 1.f;
    int o = (b * 4096 + l) * 256 + c;
    qf[o] = oq; kf[o] = ok; vf[o] = ov;
}

// ---------------- KV = K^T V (per b,head) + Ksum; float4 outer product ----------------
__global__ void kv_part(const float* __restrict__ kf, const float* __restrict__ vf,
                        float* __restrict__ kvp, float* __restrict__ kspart) {
    __shared__ float red[4][1024];
    __shared__ float kred[4][32];
    int bid = blockIdx.x;            // bnh*16 + ch
    int bnh = bid >> 4, ch = bid & 15;
    int b = bnh >> 3, nh = bnh & 7;
    int t = threadIdx.x;
    int ls = t >> 6, dkg = (t >> 3) & 7, dvg = t & 7;
    const float* kb = kf + (size_t)b * 4096 * 256 + nh * 32 + dkg * 4;
    const float* vb = vf + (size_t)b * 4096 * 256 + nh * 32 + dvg * 4;
    int l0 = ch * 256 + ls * 64;
    float4 a0 = {0,0,0,0}, a1 = a0, a2 = a0, a3 = a0, ks = a0;
    for (int l = l0; l < l0 + 64; l++) {
        float4 k4 = *(const float4*)(kb + (size_t)l * 256);
        float4 v4 = *(const float4*)(vb + (size_t)l * 256);
        a0.x += k4.x * v4.x; a0.y += k4.x * v4.y; a0.z += k4.x * v4.z; a0.w += k4.x * v4.w;
        a1.x += k4.y * v4.x; a1.y += k4.y * v4.y; a1.z += k4.y * v4.z; a1.w += k4.y * v4.w;
        a2.x += k4.z * v4.x; a2.y += k4.z * v4.y; a2.z += k4.z * v4.z; a2.w += k4.z * v4.w;
        a3.x += k4.w * v4.x; a3.y += k4.w * v4.y; a3.z += k4.w * v4.z; a3.w += k4.w * v4.w;
        ks.x += k4.x; ks.y += k4.y; ks.z += k4.z; ks.w += k4.w;
    }
    int base = dkg * 128 + dvg * 4;
    *(float4*)(&red[ls][base])      = a0;
    *(float4*)(&red[ls][base + 32]) = a1;
    *(float4*)(&red[ls][base + 64]) = a2;
    *(float4*)(&red[ls][base + 96]) = a3;
    if (dvg == 0) *(float4*)(&kred[ls][dkg * 4]) = ks;
    __syncthreads();
    for (int e = t; e < 1024; e += 256)
        kvp[bid * 1024 + e] = red[0][e] + red[1][e] + red[2][e] + red[3][e];
    if (t < 32) kspart[bid * 32 + t] = kred[0][t] + kred[1][t] + kred[2][t] + kred[3][t];
}

__global__ void kv_red(const float* __restrict__ kvp, const float* __restrict__ kspart,
                       float* __restrict__ kv, float* __restrict__ ksum) {
    int bnh = blockIdx.x;
    int t = threadIdx.x;
    for (int e = t; e < 1024; e += 256) {
        float s = 0.f;
        for (int ch = 0; ch < 16; ch++) s += kvp[(bnh * 16 + ch) * 1024 + e];
        kv[bnh * 1024 + e] = s;
    }
    if (t < 32) {
        float s = 0.f;
        for (int ch = 0; ch < 16; ch++) s += kspart[(bnh * 16 + ch) * 32 + t];
        ksum[bnh * 32 + t] = s;
    }
}

// ---------------- msg = Q*KV*Z, then merge GEMM; 8 tokens/block ----------------
__global__ void msgmerge_k(const float* __restrict__ qf, const float* __restrict__ kv,
                           const float* __restrict__ ksum, const float* __restrict__ mw,
                           float* __restrict__ merged) {
    __shared__ float Qs[8 * 256];
    __shared__ float Ms[8 * 256];
    int bid = blockIdx.x;
    int b = bid >> 9, l0 = (bid & 511) * 8;
    int t = threadIdx.x;
#pragma unroll
    for (int tt = 0; tt < 8; tt++) Qs[tt * 256 + t] = qf[(b * 4096 + l0 + tt) * 256 + t];
    __syncthreads();
    int nh = t >> 5, dv = t & 31;
    const float* kvb = kv + (b * 8 + nh) * 1024 + dv;
    const float* ksb = ksum + (b * 8 + nh) * 32;
    float sacc[8] = {0, 0, 0, 0, 0, 0, 0, 0};
    float zacc[8] = {0, 0, 0, 0, 0, 0, 0, 0};
    for (int dk = 0; dk < 32; dk++) {
        float kvv = kvb[dk * 32];
        float ksv = ksb[dk];
#pragma unroll
        for (int tt = 0; tt < 8; tt++) {
            float qv = Qs[tt * 256 + nh * 32 + dk];
            sacc[tt] += qv * kvv;
            zacc[tt] += qv * ksv;
        }
    }
#pragma unroll
    for (int tt = 0; tt < 8; tt++) Ms[tt * 256 + t] = sacc[tt] / (zacc[tt] + 1e-6f);
    __syncthreads();
    float acc8[8] = {0, 0, 0, 0, 0, 0, 0, 0};
    const float* wrow = mw + t * 256;
    for (int c = 0; c < 256; c++) {
        float wv = wrow[c];
#pragma unroll
        for (int tt = 0; tt < 8; tt++) acc8[tt] += Ms[tt * 256 + c] * wv;
    }
#pragma unroll
    for (int tt = 0; tt < 8; tt++) merged[(b * 4096 + l0 + tt) * 256 + t] = acc8[tt];
}

// ---------------- fused: bilinear-up(msg) || cat -> MLP (bf16 MFMA) -> LN2 -> +x ----------------
// 1024 threads = 16 waves; 64 px/block; LDS 74KB -> 2 blocks/CU = 8 waves/SIMD.
// Verified twice: 180.1-180.9us, WRITE 131MB (no spill), MfmaUtil ~25%. Plateau confirmed
// across 6 alternative schedules (R7-R12); do not perturb.
__global__ __launch_bounds__(1024) __attribute__((amdgpu_waves_per_eu(4))) void mlp_k(
    const float* __restrict__ x, const float* __restrict__ merged,
    const uint4* __restrict__ w1img, const uint4* __restrict__ w2img,
    const float* __restrict__ g2, const float* __restrict__ b2,
    float* __restrict__ out) {
    __shared__ __align__(16) char CATB[65536];   // cat[64px][512]bf16 swz; later h1[64px][512]
    __shared__ float ps[1024];                   // [16 waves][64 px]
    __shared__ float pq[1024];
    __shared__ float mr[64];
    __shared__ float rr[64];
    const int t = threadIdx.x;
    const int lane = t & 63;
    const int l15 = lane & 15, l4 = lane >> 4;
    const int w = t >> 6;                        // 0..15
    const int X0 = blockIdx.x * 64;
    const int Y = blockIdx.y;
    const int b = blockIdx.z;

    // ---- build cat tile: x half + bilinear-upsampled msg half ----
    {
        const int p = lane;                      // px column (64)
        const int cg = w;                        // 16 channels per thread-group
#pragma unroll
        for (int it = 0; it < 2; it++) {
            int c0 = cg * 16 + it * 8;
            float v[8];
#pragma unroll
            for (int j = 0; j < 8; j++)
                v[j] = x[((b * 256 + c0 + j) * 256 + Y) * 256 + X0 + p];
            uint4 pk;
            pk.x = pk2bf(v[0], v[1]); pk.y = pk2bf(v[2], v[3]);
            pk.z = pk2bf(v[4], v[5]); pk.w = pk2bf(v[6], v[7]);
            *(uint4*)(CATB + SWZ(p, p * 1024 + c0 * 2)) = pk;
        }
        float sy = (Y - 1.5f) * 0.25f;
        int iy0 = (int)floorf(sy);
        float fy = sy - (float)iy0;
        int y0c = iy0 < 0 ? 0 : iy0;
        int y1c = (iy0 + 1) > 63 ? 63 : (iy0 + 1);
        int X = X0 + p;
        float sx = (X - 1.5f) * 0.25f;
        int ix0 = (int)floorf(sx);
        float fx = sx - (float)ix0;
        int x0c = ix0 < 0 ? 0 : ix0;
        int x1c = (ix0 + 1) > 63 ? 63 : (ix0 + 1);
        float w00 = (1.f - fy) * (1.f - fx), w01 = (1.f - fy) * fx;
        float w10 = fy * (1.f - fx), w11 = fy * fx;
        const float* m00 = merged + ((b * 64 + y0c) * 64 + x0c) * 256;
        const float* m01 = merged + ((b * 64 + y0c) * 64 + x1c) * 256;
        const float* m10 = merged + ((b * 64 + y1c) * 64 + x0c) * 256;
        const float* m11 = merged + ((b * 64 + y1c) * 64 + x1c) * 256;
#pragma unroll
        for (int it = 0; it < 2; it++) {
            int c0 = cg * 16 + it * 8;
            float v[8];
#pragma unroll
            for (int j = 0; j < 8; j++)
                v[j] = w00 * m00[c0 + j] + w01 * m01[c0 + j] + w10 * m10[c0 + j] + w11 * m11[c0 + j];
            uint4 pk;
            pk.x = pk2bf(v[0], v[1]); pk.y = pk2bf(v[2], v[3]);
            pk.z = pk2bf(v[4], v[5]); pk.w = pk2bf(v[6], v[7]);
            *(uint4*)(CATB + SWZ(p, p * 1024 + (256 + c0) * 2)) = pk;
        }
    }
    __syncthreads();

    // ---- GEMM1: 16 rounds BK=32; wave w owns j[w*32..+32); ping-pong pipeline ----
    f32x4 acc[2][4];
#pragma unroll
    for (int a = 0; a < 2; a++)
#pragma unroll
        for (int n = 0; n < 4; n++) acc[a][n] = (f32x4){0.f, 0.f, 0.f, 0.f};
    {
        const uint4* w1p = w1img + (w * 2) * 64 + lane;   // jt = w*2 + a
        bf16x8 wa0[2], wa1[2], bf0[4], bf1[4];
#pragma unroll
        for (int a = 0; a < 2; a++) wa0[a] = *(const bf16x8*)(w1p + a * 64);
#pragma unroll
        for (int n = 0; n < 4; n++) {
            int pr = n * 16 + l15;
            bf0[n] = *(const bf16x8*)(CATB + SWZ(pr, pr * 1024 + l4 * 16));
        }
#pragma unroll
        for (int it = 0; it < 8; it++) {
            int rk = it * 2;
            // issue loads for rk+1
#pragma unroll
            for (int a = 0; a < 2; a++) wa1[a] = *(const bf16x8*)(w1p + (rk + 1) * 2048 + a * 64);
#pragma unroll
            for (int n = 0; n < 4; n++) {
                int pr = n * 16 + l15;
                bf1[n] = *(const bf16x8*)(CATB + SWZ(pr, pr * 1024 + (rk + 1) * 64 + l4 * 16));
            }
            // MFMA round rk (wa0/bf0)
#pragma unroll
            for (int n = 0; n < 4; n++)
#pragma unroll
                for (int a = 0; a < 2; a++)
                    acc[a][n] = __builtin_amdgcn_mfma_f32_16x16x32_bf16(wa0[a], bf0[n], acc[a][n], 0, 0, 0);
            // issue loads for rk+2
            if (it < 7) {
#pragma unroll
                for (int a = 0; a < 2; a++) wa0[a] = *(const bf16x8*)(w1p + (rk + 2) * 2048 + a * 64);
#pragma unroll
                for (int n = 0; n < 4; n++) {
                    int pr = n * 16 + l15;
                    bf0[n] = *(const bf16x8*)(CATB + SWZ(pr, pr * 1024 + (rk + 2) * 64 + l4 * 16));
                }
            }
            // MFMA round rk+1 (wa1/bf1)
#pragma unroll
            for (int n = 0; n < 4; n++)
#pragma unroll
                for (int a = 0; a < 2; a++)
                    acc[a][n] = __builtin_amdgcn_mfma_f32_16x16x32_bf16(wa1[a], bf1[n], acc[a][n], 0, 0, 0);
        }
    }

    // ---- stash x-residual (bf16 pairs) for epilogue before h1 overlays CATB ----
    // GEMM2 wave tile: c[w*16..+16) x px[0..64); this thread's c = w*16 + l4*4 + r
    uint2 xs[4];
    {
        int c0 = w * 16 + l4 * 4;
#pragma unroll
        for (int n = 0; n < 4; n++) {
            int px = n * 16 + l15;
            xs[n] = *(const uint2*)(CATB + SWZ(px, px * 1024 + c0 * 2));
        }
    }
    __syncthreads();

    // ---- write relu(h1) into CATB (overlay), rows=px, cols=j ----
#pragma unroll
    for (int a = 0; a < 2; a++) {
        int j0 = w * 32 + a * 16 + l4 * 4;
#pragma unroll
        for (int n = 0; n < 4; n++) {
            int pr = n * 16 + l15;
            uint2 u;
            u.x = pk2bf(fmaxf(acc[a][n][0], 0.f), fmaxf(acc[a][n][1], 0.f));
            u.y = pk2bf(fmaxf(acc[a][n][2], 0.f), fmaxf(acc[a][n][3], 0.f));
            *(uint2*)(CATB + SWZ(pr, pr * 1024 + j0 * 2)) = u;
        }
    }
    __syncthreads();

    // ---- GEMM2: 16 rounds BK=32; wave w owns c[w*16..+16); ping-pong pipeline ----
    f32x4 macc[4];
#pragma unroll
    for (int n = 0; n < 4; n++) macc[n] = (f32x4){0.f, 0.f, 0.f, 0.f};
    {
        const uint4* w2p = w2img + w * 64 + lane;         // ct = w
        bf16x8 va0, va1, bf0[4], bf1[4];
        va0 = *(const bf16x8*)(w2p);
#pragma unroll
        for (int n = 0; n < 4; n++) {
            int pr = n * 16 + l15;
            bf0[n] = *(const bf16x8*)(CATB + SWZ(pr, pr * 1024 + l4 * 16));
        }
#pragma unroll
        for (int it = 0; it < 8; it++) {
            int rj = it * 2;
            va1 = *(const bf16x8*)(w2p + (rj + 1) * 1024);
#pragma unroll
            for (int n = 0; n < 4; n++) {
                int pr = n * 16 + l15;
                bf1[n] = *(const bf16x8*)(CATB + SWZ(pr, pr * 1024 + (rj + 1) * 64 + l4 * 16));
            }
#pragma unroll
            for (int n = 0; n < 4; n++)
                macc[n] = __builtin_amdgcn_mfma_f32_16x16x32_bf16(va0, bf0[n], macc[n], 0, 0, 0);
            if (it < 7) {
                va0 = *(const bf16x8*)(w2p + (rj + 2) * 1024);
#pragma unroll
                for (int n = 0; n < 4; n++) {
                    int pr = n * 16 + l15;
                    bf0[n] = *(const bf16x8*)(CATB + SWZ(pr, pr * 1024 + (rj + 2) * 64 + l4 * 16));
                }
            }
#pragma unroll
            for (int n = 0; n < 4; n++)
                macc[n] = __builtin_amdgcn_mfma_f32_16x16x32_bf16(va1, bf1[n], macc[n], 0, 0, 0);
        }
    }

    // ---- epilogue: cross-wave LN over c, residual from stashed bf16(x), store NCHW ----
#pragma unroll
    for (int n = 0; n < 4; n++) {
        float ss = 0.f, qq = 0.f;
#pragma unroll
        for (int r = 0; r < 4; r++) { float vv = macc[n][r]; ss += vv; qq += vv * vv; }
        ss += __shfl_xor(ss, 16); ss += __shfl_xor(ss, 32);
        qq += __shfl_xor(qq, 16); qq += __shfl_xor(qq, 32);
        if (l4 == 0) {
            ps[w * 64 + n * 16 + l15] = ss;
            pq[w * 64 + n * 16 + l15] = qq;
        }
    }
    __syncthreads();
    if (t < 64) {
        float ss = 0.f, qq = 0.f;
#pragma unroll
        for (int ww = 0; ww < 16; ww++) {
            ss += ps[ww * 64 + t];
            qq += pq[ww * 64 + t];
        }
        float mean = ss * (1.f / 256.f);
        float var = qq * (1.f / 256.f) - mean * mean;
        mr[t] = mean; rr[t] = rsqrtf(var + 1e-5f);
    }
    __syncthreads();
    {
        int cbase = w * 16 + l4 * 4;
        float gg[4], bb[4];
#pragma unroll
        for (int r = 0; r < 4; r++) { gg[r] = g2[cbase + r]; bb[r] = b2[cbase + r]; }
#pragma unroll
        for (int n = 0; n < 4; n++) {
            int px = n * 16 + l15;
            uint2 u = xs[n];
            float xr[4];
            xr[0] = bitf(u.x << 16); xr[1] = bitf(u.x & 0xffff0000u);
            xr[2] = bitf(u.y << 16); xr[3] = bitf(u.y & 0xffff0000u);
            float mean = mr[px], rs = rr[px];
#pragma unroll
            for (int r = 0; r < 4; r++) {
                out[((b * 256 + cbase + r) * 256 + Y) * 256 + X0 + px] =
                    xr[r] + (macc[n][r] - mean) * rs * gg[r] + bb[r];
            }
        }
    }
}

extern "C" void kernel_launch(void* const* d_in, const int* in_sizes, int n_in,
                              void* d_out, int out_size, void* d_ws, size_t ws_size,
                              hipStream_t stream) {
    const float* x       = (const float*)d_in[0];
    const float* source  = (const float*)d_in[1];
    const float* ln1_g   = (const float*)d_in[2];
    const float* ln1_b   = (const float*)d_in[3];
    const float* merge_w = (const float*)d_in[4];
    const float* mlp_w1  = (const float*)d_in[5];
    const float* mlp_w2  = (const float*)d_in[6];
    const float* ln2_g   = (const float*)d_in[7];
    const float* ln2_b   = (const float*)d_in[8];
    const float* q_w = (const float*)d_in[9];
    const float* q_bn_g = (const float*)d_in[10];
    const float* q_bn_b = (const float*)d_in[11];
    const float* q_bn_m = (const float*)d_in[12];
    const float* q_bn_v = (const float*)d_in[13];
    const float* k_w = (const float*)d_in[14];
    const float* k_bn_g = (const float*)d_in[15];
    const float* k_bn_b = (const float*)d_in[16];
    const float* k_bn_m = (const float*)d_in[17];
    const float* k_bn_v = (const float*)d_in[18];
    const float* v_w = (const float*)d_in[19];
    const float* v_bn_g = (const float*)d_in[20];
    const float* v_bn_b = (const float*)d_in[21];
    const float* v_bn_m = (const float*)d_in[22];
    const float* v_bn_v = (const float*)d_in[23];
    float* out = (float*)d_out;

    float* ws = (float*)d_ws;
    float* q_sp   = ws + 0;            // 2,097,152 (reused as kvp/kspart after dwconv)
    float* s_sp   = ws + 2097152;      // 2,097,152
    float* qf     = ws + 4194304;      // 2,097,152
    float* kf     = ws + 6291456;      // 2,097,152
    float* vf     = ws + 8388608;      // 2,097,152
    float* merged = ws + 10485760;     // 2,097,152
    float* kvp    = ws + 0;            // 262,144 (overlays dead q_sp)
    float* kspart = ws + 262144;       // 8,192
    float* kv     = ws + 12650496;     // 16,384
    float* ksum   = ws + 12666880;     // 512
    uint4* w1img  = (uint4*)((char*)d_ws + 50669568);  // 512 KB
    uint4* w2img  = (uint4*)((char*)d_ws + 51193856);  // 256 KB

    build_wimg<<<192, 256, 0, stream>>>(mlp_w1, mlp_w2, w1img, w2img);
    poolln_k<<<dim3(64, 2, 2), 512, 0, stream>>>(x, source, ln1_g, ln1_b, q_sp, s_sp);
    dwconv_k<<<8192, 256, 0, stream>>>(q_sp, s_sp,
                                       q_w, q_bn_g, q_bn_b, q_bn_m, q_bn_v,
                                       k_w, k_bn_g, k_bn_b, k_bn_m, k_bn_v,
                                       v_w, v_bn_g, v_bn_b, v_bn_m, v_bn_v,
                                       qf, kf, vf);
    kv_part<<<256, 256, 0, stream>>>(kf, vf, kvp, kspart);
    kv_red<<<16, 256, 0, stream>>>(kvp, kspart, kv, ksum);
    msgmerge_k<<<1024, 256, 0, stream>>>(qf, kv, ksum, merge_w, merged);
    mlp_k<<<dim3(4, 256, 2), 1024, 0, stream>>>(x, merged, w1img, w2img, ln2_g, ln2_b, out);
}